// Round 5
// baseline (447.340 us; speedup 1.0000x reference)
//
#include <hip/hip_runtime.h>

#define D_SZ 768
#define N_SZ 50000
#define L_SZ 28
#define B_SZ 1024
#define NP   50048   // 391 * 128 (padded N)
#define NT   391     // n-tiles of 128

typedef __bf16 bf16x8 __attribute__((ext_vector_type(8)));
typedef float f32x4 __attribute__((ext_vector_type(4)));
typedef unsigned short u16x8 __attribute__((ext_vector_type(8)));

__device__ __forceinline__ unsigned short f2bf(float f) {
  union { float f; unsigned u; } v; v.f = f;
  unsigned r = v.u + 0x7FFFu + ((v.u >> 16) & 1u);
  return (unsigned short)(r >> 16);
}
__device__ __forceinline__ unsigned cvt_pk_bf16(float lo, float hi) {
  unsigned r;
  asm("v_cvt_pk_bf16_f32 %0, %1, %2" : "=v"(r) : "v"(lo), "v"(hi));
  return r;
}

// ---------------------------------------------------------------------------
// Streaming f32 -> bf16 convert, 8 elems/thread.
// ---------------------------------------------------------------------------
__global__ void conv8(const float* __restrict__ in, unsigned short* __restrict__ out, int n8)
{
  const int t = blockIdx.x * 256 + threadIdx.x;
  if (t >= n8) return;
  const float4 a0 = *(const float4*)(in + (size_t)t * 8);
  const float4 a1 = *(const float4*)(in + (size_t)t * 8 + 4);
  uint4 o;
  o.x = cvt_pk_bf16(a0.x, a0.y);
  o.y = cvt_pk_bf16(a0.z, a0.w);
  o.z = cvt_pk_bf16(a1.x, a1.y);
  o.w = cvt_pk_bf16(a1.z, a1.w);
  *(uint4*)(out + (size_t)t * 8) = o;
}

// ---------------------------------------------------------------------------
// Projection GEMM: Y[M][768] bf16 = X @ W^T. 128x128 tile, BK=32, 4 waves.
// Co-XCD id swizzle: the 6 col-blocks sharing one X row-tile land on the same
// XCD (id%8 == y%8) so the X tile is L2-resident after the first fetch.
// id = (y%8) + 8*(x + 6*(y/8)); y<8 -> features, else ex tile (y-8).
// ---------------------------------------------------------------------------
__global__ __launch_bounds__(256, 2)
void proj_gemm2(const unsigned short* __restrict__ Xfb,
                const unsigned short* __restrict__ Xeb,
                const float* __restrict__ Xef,
                const unsigned short* __restrict__ Wb,
                unsigned short* __restrict__ Yf, unsigned short* __restrict__ Ye,
                float* __restrict__ ssqF, float* __restrict__ ssqE,
                int exBf)
{
  const int id = blockIdx.x;
  const int slot = id & 7, rest = id >> 3;
  const int x = rest % 6, yq = rest / 6;
  const int y = yq * 8 + slot;
  if (y >= 8 + NT) return;

  __shared__ __align__(16) unsigned short As[128 * 32];
  __shared__ __align__(16) unsigned short Bs[128 * 32];
  const int tid = threadIdx.x;
  const int w = tid >> 6, lane = tid & 63;
  const int wr = w >> 1, wc = w & 1;
  const int fr = lane & 15, fq = lane >> 4;
  const int fk = fq << 3;
  const int srow = lane >> 2;
  const int scol = (lane & 3) << 3;
  const int o0 = x * 128;

  const unsigned short* Xb; const float* Xf32; unsigned short* Y;
  float* ssqG; int m0, Mvalid; bool abf;
  if (y < 8) { Xb = Xfb; Xf32 = nullptr; Y = Yf; ssqG = ssqF; m0 = y * 128; Mvalid = B_SZ; abf = true; }
  else { Xb = Xeb; Xf32 = Xef; Y = Ye; ssqG = ssqE; m0 = (y - 8) * 128; Mvalid = N_SZ; abf = (exBf != 0); }

  f32x4 acc[4][4] = {};

  for (int kk = 0; kk < D_SZ; kk += 32) {
    if (abf) {
#pragma unroll
      for (int i = 0; i < 2; ++i) {
        const int chunk = w * 2 + i;
        const int row = chunk * 16 + srow;
        const unsigned short* ga = Xb + (size_t)(m0 + row) * D_SZ + kk + scol;
        __builtin_amdgcn_global_load_lds((const __attribute__((address_space(1))) void*)ga,
                                         (__attribute__((address_space(3))) void*)&As[chunk * 512],
                                         16, 0, 0);
      }
    } else {
#pragma unroll
      for (int i = 0; i < 2; ++i) {
        const int idx = tid + i * 256;
        const int row = idx >> 2;
        const int c8 = (idx & 3) << 3;
        float4 a0, a1;
        if (m0 + row < Mvalid) {
          const float* p = Xf32 + (size_t)(m0 + row) * D_SZ + kk + c8;
          a0 = *(const float4*)p; a1 = *(const float4*)(p + 4);
        } else { a0 = make_float4(0.f, 0.f, 0.f, 0.f); a1 = a0; }
        u16x8 av;
        av[0] = f2bf(a0.x); av[1] = f2bf(a0.y); av[2] = f2bf(a0.z); av[3] = f2bf(a0.w);
        av[4] = f2bf(a1.x); av[5] = f2bf(a1.y); av[6] = f2bf(a1.z); av[7] = f2bf(a1.w);
        *(u16x8*)&As[row * 32 + c8] = av;
      }
    }
#pragma unroll
    for (int i = 0; i < 2; ++i) {
      const int chunk = w * 2 + i;
      const int row = chunk * 16 + srow;
      const unsigned short* gb = Wb + (size_t)(o0 + row) * D_SZ + kk + scol;
      __builtin_amdgcn_global_load_lds((const __attribute__((address_space(1))) void*)gb,
                                       (__attribute__((address_space(3))) void*)&Bs[chunk * 512],
                                       16, 0, 0);
    }
    __syncthreads();
    bf16x8 af[4], bfv[4];
#pragma unroll
    for (int i = 0; i < 4; ++i) {
      af[i]  = *(const bf16x8*)&As[(wr * 64 + i * 16 + fr) * 32 + fk];
      bfv[i] = *(const bf16x8*)&Bs[(wc * 64 + i * 16 + fr) * 32 + fk];
    }
#pragma unroll
    for (int mi = 0; mi < 4; ++mi)
#pragma unroll
      for (int ni = 0; ni < 4; ++ni)
        acc[mi][ni] = __builtin_amdgcn_mfma_f32_16x16x32_bf16(af[mi], bfv[ni], acc[mi][ni], 0, 0, 0);
    __syncthreads();
  }

  float ssq[4][4] = {};
#pragma unroll
  for (int mi = 0; mi < 4; ++mi)
#pragma unroll
    for (int ni = 0; ni < 4; ++ni)
#pragma unroll
      for (int r = 0; r < 4; ++r) {
        const int row = m0 + wr * 64 + mi * 16 + fq * 4 + r;
        const int col = o0 + wc * 64 + ni * 16 + fr;
        const float v = acc[mi][ni][r];
        Y[(size_t)row * D_SZ + col] = f2bf(v);
        ssq[mi][r] += v * v;
      }
#pragma unroll
  for (int mi = 0; mi < 4; ++mi)
#pragma unroll
    for (int r = 0; r < 4; ++r) {
      float v = ssq[mi][r];
      v += __shfl_xor(v, 1); v += __shfl_xor(v, 2);
      v += __shfl_xor(v, 4); v += __shfl_xor(v, 8);
      if (fr == 0) atomicAdd(&ssqG[m0 + wr * 64 + mi * 16 + fq * 4 + r], v);
    }
}

// ---------------------------------------------------------------------------
// Build excT bf16 [32][NP] + fused per-class counts.
// ---------------------------------------------------------------------------
__global__ void excT_prep(const float* __restrict__ exc, unsigned short* __restrict__ excT,
                          float* __restrict__ counts)
{
  __shared__ float lds[64][29];
  const int n0 = blockIdx.x * 64;
  const int tid = threadIdx.x;
  for (int i = tid; i < 64 * L_SZ; i += 256) {
    const int n = i / L_SZ, l = i % L_SZ;
    lds[n][l] = (n0 + n < N_SZ) ? exc[(size_t)(n0 + n) * L_SZ + l] : 0.0f;
  }
  __syncthreads();
  if (tid < L_SZ) {
    float c = 0.f;
    for (int n = 0; n < 64; ++n) c += lds[n][tid];
    atomicAdd(&counts[tid], c);
  }
  for (int i = tid; i < 32 * 64; i += 256) {
    const int l = i >> 6, n = i & 63;
    const float v = (l < L_SZ) ? lds[n][l] : 0.0f;
    excT[(size_t)l * NP + n0 + n] = f2bf(v);
  }
}

// ---------------------------------------------------------------------------
// Fused s-GEMM. 4 n-tiles per block (grid 98x8 = 784 blocks ~= 3 blocks/CU
// for latency hiding). Co-XCD id swizzle: the 8 m-blocks consuming the same
// exfn 4-tile slab (786 KB, fits one XCD L2) land on one XCD (id%8 == x%8).
// id = (x%8) + 8*(m + 8*(x/8)), x in [0,98).
// ---------------------------------------------------------------------------
__global__ __launch_bounds__(256, 3)
void echo_gemm(const unsigned short* __restrict__ fn,
               const unsigned short* __restrict__ exfn,
               const unsigned short* __restrict__ excT,
               const float* __restrict__ ssqF,
               const float* __restrict__ ssqE,
               float* __restrict__ echo)
{
  const int id = blockIdx.x;
  const int slot = id & 7, rest = id >> 3;
  const int m = rest & 7, xq = rest >> 3;
  const int x = xq * 8 + slot;
  if (x >= 98) return;
  const int m0 = m * 128;

  __shared__ __align__(16) unsigned short As[128 * 32];
  __shared__ __align__(16) unsigned short Bs[128 * 32];
  __shared__ __align__(16) unsigned short Al[128 * 128];
  const int tid = threadIdx.x;
  const int w = tid >> 6, lane = tid & 63;
  const int wr = w >> 1, wc = w & 1;
  const int fr = lane & 15, fq = lane >> 4;
  const int fk = fq << 3;
  const int srow = lane >> 2;
  const int scol = (lane & 3) << 3;

  float rf[4][4];
#pragma unroll
  for (int mi = 0; mi < 4; ++mi)
#pragma unroll
    for (int r = 0; r < 4; ++r)
      rf[mi][r] = 1.0f / fmaxf(sqrtf(ssqF[m0 + wr * 64 + mi * 16 + fq * 4 + r]), 1e-12f);

  f32x4 acc2[2][2] = {};

  for (int ti = 0; ti < 4; ++ti) {
    const int t = x * 4 + ti;
    if (t >= NT) break;
    const int n0 = t * 128;
    f32x4 acc[4][4] = {};
    for (int kk = 0; kk < D_SZ; kk += 32) {
#pragma unroll
      for (int i = 0; i < 2; ++i) {
        const int chunk = w * 2 + i;
        const int row = chunk * 16 + srow;
        const unsigned short* ga = fn + (size_t)(m0 + row) * D_SZ + kk + scol;
        const unsigned short* gb = exfn + (size_t)(n0 + row) * D_SZ + kk + scol;
        __builtin_amdgcn_global_load_lds((const __attribute__((address_space(1))) void*)ga,
                                         (__attribute__((address_space(3))) void*)&As[chunk * 512],
                                         16, 0, 0);
        __builtin_amdgcn_global_load_lds((const __attribute__((address_space(1))) void*)gb,
                                         (__attribute__((address_space(3))) void*)&Bs[chunk * 512],
                                         16, 0, 0);
      }
      __syncthreads();
      bf16x8 af[4], bfv[4];
#pragma unroll
      for (int i = 0; i < 4; ++i) {
        af[i]  = *(const bf16x8*)&As[(wr * 64 + i * 16 + fr) * 32 + fk];
        bfv[i] = *(const bf16x8*)&Bs[(wc * 64 + i * 16 + fr) * 32 + fk];
      }
#pragma unroll
      for (int mi = 0; mi < 4; ++mi)
#pragma unroll
        for (int ni = 0; ni < 4; ++ni)
          acc[mi][ni] = __builtin_amdgcn_mfma_f32_16x16x32_bf16(af[mi], bfv[ni], acc[mi][ni], 0, 0, 0);
      __syncthreads();
    }
    // scale to cosine, cube, stage a = s^3 into XOR-swizzled LDS tile [b][n]
    float rne[4];
#pragma unroll
    for (int ni = 0; ni < 4; ++ni)
      rne[ni] = 1.0f / fmaxf(sqrtf(ssqE[n0 + wc * 64 + ni * 16 + fr]), 1e-12f);
#pragma unroll
    for (int mi = 0; mi < 4; ++mi)
#pragma unroll
      for (int ni = 0; ni < 4; ++ni)
#pragma unroll
        for (int r = 0; r < 4; ++r) {
          const int b = wr * 64 + mi * 16 + fq * 4 + r;
          const int n = wc * 64 + ni * 16 + fr;
          const float s = acc[mi][ni][r] * rf[mi][r] * rne[ni];
          const unsigned byte = (((unsigned)(b * 128 + n)) << 1) ^ ((unsigned)(b & 7) << 4);
          *(unsigned short*)((char*)Al + byte) = f2bf(s * s * s);
        }
    __syncthreads();
    // stage 2: echo_part[b][cls] += a[b][n] * excT[cls][n]
#pragma unroll
    for (int kk2 = 0; kk2 < 128; kk2 += 32) {
      bf16x8 pa[2], pb[2];
#pragma unroll
      for (int i = 0; i < 2; ++i) {
        const int b = w * 32 + i * 16 + fr;
        const unsigned byte = (((unsigned)(b * 128 + kk2 + fk)) << 1) ^ ((unsigned)(b & 7) << 4);
        pa[i] = *(const bf16x8*)((const char*)Al + byte);
        const int cls = i * 16 + fr;
        pb[i] = *(const bf16x8*)(excT + (size_t)cls * NP + n0 + kk2 + fk);
      }
#pragma unroll
      for (int mi = 0; mi < 2; ++mi)
#pragma unroll
        for (int ni = 0; ni < 2; ++ni)
          acc2[mi][ni] = __builtin_amdgcn_mfma_f32_16x16x32_bf16(pa[mi], pb[ni], acc2[mi][ni], 0, 0, 0);
    }
    __syncthreads();
  }
#pragma unroll
  for (int mi = 0; mi < 2; ++mi)
#pragma unroll
    for (int ni = 0; ni < 2; ++ni)
#pragma unroll
      for (int r = 0; r < 4; ++r) {
        const int b = w * 32 + mi * 16 + fq * 4 + r;
        const int cls = ni * 16 + fr;
        if (cls < L_SZ)
          atomicAdd(&echo[(size_t)(m0 + b) * L_SZ + cls], acc2[mi][ni][r]);
      }
}

// ---------------------------------------------------------------------------
// Finalize: echo/counts -> neg_dists (vs real class_reps) -> BCE loss.
// ---------------------------------------------------------------------------
__global__ __launch_bounds__(1024)
void finalize(const float* __restrict__ echo, const float* __restrict__ counts,
              const float* __restrict__ labels, const float* __restrict__ creps,
              float* __restrict__ out)
{
  __shared__ float C[L_SZ * L_SZ];
  __shared__ float cnt[L_SZ];
  __shared__ float red[16];
  const int tid = threadIdx.x;
  if (tid < L_SZ * L_SZ) C[tid] = creps[tid];
  if (tid >= 896 && tid < 896 + L_SZ) cnt[tid - 896] = counts[tid - 896];
  __syncthreads();
  float e[L_SZ];
#pragma unroll
  for (int l = 0; l < L_SZ; ++l) e[l] = echo[tid * L_SZ + l] / cnt[l];
  float lsum = 0.f;
  for (int j = 0; j < L_SZ; ++j) {
    float d2 = 0.f;
#pragma unroll
    for (int l = 0; l < L_SZ; ++l) { const float df = e[l] - C[j * L_SZ + l]; d2 += df * df; }
    const float nd = -sqrtf(d2);
    out[1 + tid * L_SZ + j] = nd;
    const float y = labels[tid * L_SZ + j];
    const float sp = fmaxf(nd, 0.f) + log1pf(expf(-fabsf(nd)));
    lsum += sp - nd * y;
  }
#pragma unroll
  for (int o = 32; o; o >>= 1) lsum += __shfl_xor(lsum, o);
  if ((tid & 63) == 0) red[tid >> 6] = lsum;
  __syncthreads();
  if (tid < 16) {
    float v = red[tid];
#pragma unroll
    for (int o = 8; o; o >>= 1) v += __shfl_xor(v, o);
    if (tid == 0) out[0] = v * (1.0f / (B_SZ * L_SZ));
  }
}

extern "C" void kernel_launch(void* const* d_in, const int* in_sizes, int n_in,
                              void* d_out, int out_size, void* d_ws, size_t ws_size,
                              hipStream_t stream)
{
  (void)in_sizes; (void)n_in; (void)out_size;
  const float* features = (const float*)d_in[0];
  const float* labels   = (const float*)d_in[1];
  const float* W_g      = (const float*)d_in[2];
  const float* ex_feat  = (const float*)d_in[3];
  const float* ex_cls   = (const float*)d_in[4];
  const float* creps    = (const float*)d_in[5];
  float* out = (float*)d_out;

  const size_t OFF_EXFN = 0;
  const size_t OFF_FN   = OFF_EXFN + (size_t)NP * D_SZ * 2;
  const size_t OFF_EXCT = OFF_FN + (size_t)B_SZ * D_SZ * 2;
  const size_t OFF_WB   = OFF_EXCT;                                // alias (disjoint lifetime)
  const size_t OFF_FNXB = OFF_EXCT + (size_t)D_SZ * D_SZ * 2;
  const size_t OFF_ECHO = OFF_EXCT + (size_t)32 * NP * 2;
  const size_t OFF_SSQE = OFF_ECHO + (size_t)B_SZ * L_SZ * 4;
  const size_t OFF_SSQF = OFF_SSQE + (size_t)NP * 4;
  const size_t OFF_CNT  = OFF_SSQF + (size_t)B_SZ * 4;
  const size_t NEED_B   = OFF_CNT + 128;
  const size_t OFF_XBE  = NEED_B;
  const size_t NEED_A   = OFF_XBE + (size_t)NP * D_SZ * 2;
  if (ws_size < NEED_B) return;
  const int useA = (ws_size >= NEED_A) ? 1 : 0;

  char* ws = (char*)d_ws;
  unsigned short* exfn = (unsigned short*)(ws + OFF_EXFN);
  unsigned short* fnb  = (unsigned short*)(ws + OFF_FN);
  unsigned short* excT = (unsigned short*)(ws + OFF_EXCT);
  unsigned short* Wb   = (unsigned short*)(ws + OFF_WB);
  unsigned short* fnXb = (unsigned short*)(ws + OFF_FNXB);
  float* echo   = (float*)(ws + OFF_ECHO);
  float* ssqE   = (float*)(ws + OFF_SSQE);
  float* ssqF   = (float*)(ws + OFF_SSQF);
  float* counts = (float*)(ws + OFF_CNT);
  unsigned short* Xbe = (unsigned short*)(ws + OFF_XBE);

  // zero echo + ssqE + ssqF + counts (contiguous span)
  hipMemsetAsync(ws + OFF_ECHO, 0, OFF_CNT + 128 - OFF_ECHO, stream);

  if (useA) {
    hipMemsetAsync((char*)Xbe + (size_t)N_SZ * D_SZ * 2, 0,
                   (size_t)(NP - N_SZ) * D_SZ * 2, stream);
    conv8<<<dim3((N_SZ * D_SZ / 8 + 255) / 256), 256, 0, stream>>>(ex_feat, Xbe, N_SZ * D_SZ / 8);
  }
  conv8<<<dim3((B_SZ * D_SZ / 8 + 255) / 256), 256, 0, stream>>>(features, fnXb, B_SZ * D_SZ / 8);
  conv8<<<dim3((D_SZ * D_SZ / 8 + 255) / 256), 256, 0, stream>>>(W_g, Wb, D_SZ * D_SZ / 8);

  // grid: id = (y%8) + 8*(x + 6*(y/8)), y in [0,399), x in [0,6)
  proj_gemm2<<<dim3(8 * 6 * 50), 256, 0, stream>>>(fnXb, Xbe, ex_feat, Wb,
                                                   fnb, exfn, ssqF, ssqE, useA);

  excT_prep<<<dim3(NP / 64), 256, 0, stream>>>(ex_cls, excT, counts);  // clobbers Wb/fnXb (done)
  // grid: id = (x%8) + 8*(m + 8*(x/8)), x in [0,98), m in [0,8)
  echo_gemm<<<dim3(8 * 8 * 13), 256, 0, stream>>>(fnb, exfn, excT, ssqF, ssqE, echo);
  finalize<<<dim3(1), 1024, 0, stream>>>(echo, counts, labels, creps, out);
}

// Round 6
// 346.072 us; speedup vs baseline: 1.2926x; 1.2926x over previous
//
#include <hip/hip_runtime.h>

#define D_SZ 768
#define N_SZ 50000
#define L_SZ 28
#define B_SZ 1024
#define NP   50048   // 391 * 128 (padded N)
#define NT   391     // n-tiles of 128

typedef __bf16 bf16x8 __attribute__((ext_vector_type(8)));
typedef float f32x4 __attribute__((ext_vector_type(4)));
typedef unsigned short u16x8 __attribute__((ext_vector_type(8)));

__device__ __forceinline__ unsigned short f2bf(float f) {
  union { float f; unsigned u; } v; v.f = f;
  unsigned r = v.u + 0x7FFFu + ((v.u >> 16) & 1u);
  return (unsigned short)(r >> 16);
}
__device__ __forceinline__ unsigned cvt_pk_bf16(float lo, float hi) {
  unsigned r;
  asm("v_cvt_pk_bf16_f32 %0, %1, %2" : "=v"(r) : "v"(lo), "v"(hi));
  return r;
}

// ---------------------------------------------------------------------------
// Streaming f32 -> bf16 convert, 8 elems/thread.
// ---------------------------------------------------------------------------
__global__ void conv8(const float* __restrict__ in, unsigned short* __restrict__ out, int n8)
{
  const int t = blockIdx.x * 256 + threadIdx.x;
  if (t >= n8) return;
  const float4 a0 = *(const float4*)(in + (size_t)t * 8);
  const float4 a1 = *(const float4*)(in + (size_t)t * 8 + 4);
  uint4 o;
  o.x = cvt_pk_bf16(a0.x, a0.y);
  o.y = cvt_pk_bf16(a0.z, a0.w);
  o.z = cvt_pk_bf16(a1.x, a1.y);
  o.w = cvt_pk_bf16(a1.z, a1.w);
  *(uint4*)(out + (size_t)t * 8) = o;
}

// ---------------------------------------------------------------------------
// Projection GEMM: Y[M][768] bf16 = X @ W^T. 128x128 tile, BK=32, 4 waves.
// Co-XCD id swizzle: id = (y%8) + 8*(x + 6*(y/8)).
// ---------------------------------------------------------------------------
__global__ __launch_bounds__(256, 2)
void proj_gemm2(const unsigned short* __restrict__ Xfb,
                const unsigned short* __restrict__ Xeb,
                const float* __restrict__ Xef,
                const unsigned short* __restrict__ Wb,
                unsigned short* __restrict__ Yf, unsigned short* __restrict__ Ye,
                float* __restrict__ ssqF, float* __restrict__ ssqE,
                int exBf)
{
  const int id = blockIdx.x;
  const int slot = id & 7, rest = id >> 3;
  const int x = rest % 6, yq = rest / 6;
  const int y = yq * 8 + slot;
  if (y >= 8 + NT) return;

  __shared__ __align__(16) unsigned short As[128 * 32];
  __shared__ __align__(16) unsigned short Bs[128 * 32];
  const int tid = threadIdx.x;
  const int w = tid >> 6, lane = tid & 63;
  const int wr = w >> 1, wc = w & 1;
  const int fr = lane & 15, fq = lane >> 4;
  const int fk = fq << 3;
  const int srow = lane >> 2;
  const int scol = (lane & 3) << 3;
  const int o0 = x * 128;

  const unsigned short* Xb; const float* Xf32; unsigned short* Y;
  float* ssqG; int m0, Mvalid; bool abf;
  if (y < 8) { Xb = Xfb; Xf32 = nullptr; Y = Yf; ssqG = ssqF; m0 = y * 128; Mvalid = B_SZ; abf = true; }
  else { Xb = Xeb; Xf32 = Xef; Y = Ye; ssqG = ssqE; m0 = (y - 8) * 128; Mvalid = N_SZ; abf = (exBf != 0); }

  f32x4 acc[4][4] = {};

  for (int kk = 0; kk < D_SZ; kk += 32) {
    if (abf) {
#pragma unroll
      for (int i = 0; i < 2; ++i) {
        const int chunk = w * 2 + i;
        const int row = chunk * 16 + srow;
        const unsigned short* ga = Xb + (size_t)(m0 + row) * D_SZ + kk + scol;
        __builtin_amdgcn_global_load_lds((const __attribute__((address_space(1))) void*)ga,
                                         (__attribute__((address_space(3))) void*)&As[chunk * 512],
                                         16, 0, 0);
      }
    } else {
#pragma unroll
      for (int i = 0; i < 2; ++i) {
        const int idx = tid + i * 256;
        const int row = idx >> 2;
        const int c8 = (idx & 3) << 3;
        float4 a0, a1;
        if (m0 + row < Mvalid) {
          const float* p = Xf32 + (size_t)(m0 + row) * D_SZ + kk + c8;
          a0 = *(const float4*)p; a1 = *(const float4*)(p + 4);
        } else { a0 = make_float4(0.f, 0.f, 0.f, 0.f); a1 = a0; }
        u16x8 av;
        av[0] = f2bf(a0.x); av[1] = f2bf(a0.y); av[2] = f2bf(a0.z); av[3] = f2bf(a0.w);
        av[4] = f2bf(a1.x); av[5] = f2bf(a1.y); av[6] = f2bf(a1.z); av[7] = f2bf(a1.w);
        *(u16x8*)&As[row * 32 + c8] = av;
      }
    }
#pragma unroll
    for (int i = 0; i < 2; ++i) {
      const int chunk = w * 2 + i;
      const int row = chunk * 16 + srow;
      const unsigned short* gb = Wb + (size_t)(o0 + row) * D_SZ + kk + scol;
      __builtin_amdgcn_global_load_lds((const __attribute__((address_space(1))) void*)gb,
                                       (__attribute__((address_space(3))) void*)&Bs[chunk * 512],
                                       16, 0, 0);
    }
    __syncthreads();
    bf16x8 af[4], bfv[4];
#pragma unroll
    for (int i = 0; i < 4; ++i) {
      af[i]  = *(const bf16x8*)&As[(wr * 64 + i * 16 + fr) * 32 + fk];
      bfv[i] = *(const bf16x8*)&Bs[(wc * 64 + i * 16 + fr) * 32 + fk];
    }
#pragma unroll
    for (int mi = 0; mi < 4; ++mi)
#pragma unroll
      for (int ni = 0; ni < 4; ++ni)
        acc[mi][ni] = __builtin_amdgcn_mfma_f32_16x16x32_bf16(af[mi], bfv[ni], acc[mi][ni], 0, 0, 0);
    __syncthreads();
  }

  float ssq[4][4] = {};
#pragma unroll
  for (int mi = 0; mi < 4; ++mi)
#pragma unroll
    for (int ni = 0; ni < 4; ++ni)
#pragma unroll
      for (int r = 0; r < 4; ++r) {
        const int row = m0 + wr * 64 + mi * 16 + fq * 4 + r;
        const int col = o0 + wc * 64 + ni * 16 + fr;
        const float v = acc[mi][ni][r];
        Y[(size_t)row * D_SZ + col] = f2bf(v);
        ssq[mi][r] += v * v;
      }
#pragma unroll
  for (int mi = 0; mi < 4; ++mi)
#pragma unroll
    for (int r = 0; r < 4; ++r) {
      float v = ssq[mi][r];
      v += __shfl_xor(v, 1); v += __shfl_xor(v, 2);
      v += __shfl_xor(v, 4); v += __shfl_xor(v, 8);
      if (fr == 0) atomicAdd(&ssqG[m0 + wr * 64 + mi * 16 + fq * 4 + r], v);
    }
}

// ---------------------------------------------------------------------------
// Build excT bf16 [32][NP] + fused per-class counts.
// ---------------------------------------------------------------------------
__global__ void excT_prep(const float* __restrict__ exc, unsigned short* __restrict__ excT,
                          float* __restrict__ counts)
{
  __shared__ float lds[64][29];
  const int n0 = blockIdx.x * 64;
  const int tid = threadIdx.x;
  for (int i = tid; i < 64 * L_SZ; i += 256) {
    const int n = i / L_SZ, l = i % L_SZ;
    lds[n][l] = (n0 + n < N_SZ) ? exc[(size_t)(n0 + n) * L_SZ + l] : 0.0f;
  }
  __syncthreads();
  if (tid < L_SZ) {
    float c = 0.f;
    for (int n = 0; n < 64; ++n) c += lds[n][tid];
    atomicAdd(&counts[tid], c);
  }
  for (int i = tid; i < 32 * 64; i += 256) {
    const int l = i >> 6, n = i & 63;
    const float v = (l < L_SZ) ? lds[n][l] : 0.0f;
    excT[(size_t)l * NP + n0 + n] = f2bf(v);
  }
}

// ---------------------------------------------------------------------------
// Fused s-GEMM. 4 n-tiles per block (grid 784 blocks ~= 3 blocks/CU, LDS-
// limited). NO register cap: (256,2) -> VGPR 116, no scratch spills; HW still
// fits 3 blocks/CU (3 waves/SIMD x 116 = 348 <= 512 VGPRs).
// Co-XCD id swizzle: id = (x%8) + 8*(m + 8*(x/8)), x in [0,98).
// ---------------------------------------------------------------------------
__global__ __launch_bounds__(256, 2)
void echo_gemm(const unsigned short* __restrict__ fn,
               const unsigned short* __restrict__ exfn,
               const unsigned short* __restrict__ excT,
               const float* __restrict__ ssqF,
               const float* __restrict__ ssqE,
               float* __restrict__ echo)
{
  const int id = blockIdx.x;
  const int slot = id & 7, rest = id >> 3;
  const int m = rest & 7, xq = rest >> 3;
  const int x = xq * 8 + slot;
  if (x >= 98) return;
  const int m0 = m * 128;

  __shared__ __align__(16) unsigned short As[128 * 32];
  __shared__ __align__(16) unsigned short Bs[128 * 32];
  __shared__ __align__(16) unsigned short Al[128 * 128];
  const int tid = threadIdx.x;
  const int w = tid >> 6, lane = tid & 63;
  const int wr = w >> 1, wc = w & 1;
  const int fr = lane & 15, fq = lane >> 4;
  const int fk = fq << 3;
  const int srow = lane >> 2;
  const int scol = (lane & 3) << 3;

  float rf[4][4];
#pragma unroll
  for (int mi = 0; mi < 4; ++mi)
#pragma unroll
    for (int r = 0; r < 4; ++r)
      rf[mi][r] = 1.0f / fmaxf(sqrtf(ssqF[m0 + wr * 64 + mi * 16 + fq * 4 + r]), 1e-12f);

  f32x4 acc2[2][2] = {};

  for (int ti = 0; ti < 4; ++ti) {
    const int t = x * 4 + ti;
    if (t >= NT) break;
    const int n0 = t * 128;
    f32x4 acc[4][4] = {};
    for (int kk = 0; kk < D_SZ; kk += 32) {
#pragma unroll
      for (int i = 0; i < 2; ++i) {
        const int chunk = w * 2 + i;
        const int row = chunk * 16 + srow;
        const unsigned short* ga = fn + (size_t)(m0 + row) * D_SZ + kk + scol;
        const unsigned short* gb = exfn + (size_t)(n0 + row) * D_SZ + kk + scol;
        __builtin_amdgcn_global_load_lds((const __attribute__((address_space(1))) void*)ga,
                                         (__attribute__((address_space(3))) void*)&As[chunk * 512],
                                         16, 0, 0);
        __builtin_amdgcn_global_load_lds((const __attribute__((address_space(1))) void*)gb,
                                         (__attribute__((address_space(3))) void*)&Bs[chunk * 512],
                                         16, 0, 0);
      }
      __syncthreads();
      bf16x8 af[4], bfv[4];
#pragma unroll
      for (int i = 0; i < 4; ++i) {
        af[i]  = *(const bf16x8*)&As[(wr * 64 + i * 16 + fr) * 32 + fk];
        bfv[i] = *(const bf16x8*)&Bs[(wc * 64 + i * 16 + fr) * 32 + fk];
      }
#pragma unroll
      for (int mi = 0; mi < 4; ++mi)
#pragma unroll
        for (int ni = 0; ni < 4; ++ni)
          acc[mi][ni] = __builtin_amdgcn_mfma_f32_16x16x32_bf16(af[mi], bfv[ni], acc[mi][ni], 0, 0, 0);
      __syncthreads();
    }
    // scale to cosine, cube, stage a = s^3 into XOR-swizzled LDS tile [b][n]
    float rne[4];
#pragma unroll
    for (int ni = 0; ni < 4; ++ni)
      rne[ni] = 1.0f / fmaxf(sqrtf(ssqE[n0 + wc * 64 + ni * 16 + fr]), 1e-12f);
#pragma unroll
    for (int mi = 0; mi < 4; ++mi)
#pragma unroll
      for (int ni = 0; ni < 4; ++ni)
#pragma unroll
        for (int r = 0; r < 4; ++r) {
          const int b = wr * 64 + mi * 16 + fq * 4 + r;
          const int n = wc * 64 + ni * 16 + fr;
          const float s = acc[mi][ni][r] * rf[mi][r] * rne[ni];
          const unsigned byte = (((unsigned)(b * 128 + n)) << 1) ^ ((unsigned)(b & 7) << 4);
          *(unsigned short*)((char*)Al + byte) = f2bf(s * s * s);
        }
    __syncthreads();
    // stage 2: echo_part[b][cls] += a[b][n] * excT[cls][n]
#pragma unroll
    for (int kk2 = 0; kk2 < 128; kk2 += 32) {
      bf16x8 pa[2], pb[2];
#pragma unroll
      for (int i = 0; i < 2; ++i) {
        const int b = w * 32 + i * 16 + fr;
        const unsigned byte = (((unsigned)(b * 128 + kk2 + fk)) << 1) ^ ((unsigned)(b & 7) << 4);
        pa[i] = *(const bf16x8*)((const char*)Al + byte);
        const int cls = i * 16 + fr;
        pb[i] = *(const bf16x8*)(excT + (size_t)cls * NP + n0 + kk2 + fk);
      }
#pragma unroll
      for (int mi = 0; mi < 2; ++mi)
#pragma unroll
        for (int ni = 0; ni < 2; ++ni)
          acc2[mi][ni] = __builtin_amdgcn_mfma_f32_16x16x32_bf16(pa[mi], pb[ni], acc2[mi][ni], 0, 0, 0);
    }
    __syncthreads();
  }
#pragma unroll
  for (int mi = 0; mi < 2; ++mi)
#pragma unroll
    for (int ni = 0; ni < 2; ++ni)
#pragma unroll
      for (int r = 0; r < 4; ++r) {
        const int b = w * 32 + mi * 16 + fq * 4 + r;
        const int cls = ni * 16 + fr;
        if (cls < L_SZ)
          atomicAdd(&echo[(size_t)(m0 + b) * L_SZ + cls], acc2[mi][ni][r]);
      }
}

// ---------------------------------------------------------------------------
// Finalize: echo/counts -> neg_dists (vs real class_reps) -> BCE loss.
// ---------------------------------------------------------------------------
__global__ __launch_bounds__(1024)
void finalize(const float* __restrict__ echo, const float* __restrict__ counts,
              const float* __restrict__ labels, const float* __restrict__ creps,
              float* __restrict__ out)
{
  __shared__ float C[L_SZ * L_SZ];
  __shared__ float cnt[L_SZ];
  __shared__ float red[16];
  const int tid = threadIdx.x;
  if (tid < L_SZ * L_SZ) C[tid] = creps[tid];
  if (tid >= 896 && tid < 896 + L_SZ) cnt[tid - 896] = counts[tid - 896];
  __syncthreads();
  float e[L_SZ];
#pragma unroll
  for (int l = 0; l < L_SZ; ++l) e[l] = echo[tid * L_SZ + l] / cnt[l];
  float lsum = 0.f;
  for (int j = 0; j < L_SZ; ++j) {
    float d2 = 0.f;
#pragma unroll
    for (int l = 0; l < L_SZ; ++l) { const float df = e[l] - C[j * L_SZ + l]; d2 += df * df; }
    const float nd = -sqrtf(d2);
    out[1 + tid * L_SZ + j] = nd;
    const float y = labels[tid * L_SZ + j];
    const float sp = fmaxf(nd, 0.f) + log1pf(expf(-fabsf(nd)));
    lsum += sp - nd * y;
  }
#pragma unroll
  for (int o = 32; o; o >>= 1) lsum += __shfl_xor(lsum, o);
  if ((tid & 63) == 0) red[tid >> 6] = lsum;
  __syncthreads();
  if (tid < 16) {
    float v = red[tid];
#pragma unroll
    for (int o = 8; o; o >>= 1) v += __shfl_xor(v, o);
    if (tid == 0) out[0] = v * (1.0f / (B_SZ * L_SZ));
  }
}

extern "C" void kernel_launch(void* const* d_in, const int* in_sizes, int n_in,
                              void* d_out, int out_size, void* d_ws, size_t ws_size,
                              hipStream_t stream)
{
  (void)in_sizes; (void)n_in; (void)out_size;
  const float* features = (const float*)d_in[0];
  const float* labels   = (const float*)d_in[1];
  const float* W_g      = (const float*)d_in[2];
  const float* ex_feat  = (const float*)d_in[3];
  const float* ex_cls   = (const float*)d_in[4];
  const float* creps    = (const float*)d_in[5];
  float* out = (float*)d_out;

  const size_t OFF_EXFN = 0;
  const size_t OFF_FN   = OFF_EXFN + (size_t)NP * D_SZ * 2;
  const size_t OFF_EXCT = OFF_FN + (size_t)B_SZ * D_SZ * 2;
  const size_t OFF_WB   = OFF_EXCT;                                // alias (disjoint lifetime)
  const size_t OFF_FNXB = OFF_EXCT + (size_t)D_SZ * D_SZ * 2;
  const size_t OFF_ECHO = OFF_EXCT + (size_t)32 * NP * 2;
  const size_t OFF_SSQE = OFF_ECHO + (size_t)B_SZ * L_SZ * 4;
  const size_t OFF_SSQF = OFF_SSQE + (size_t)NP * 4;
  const size_t OFF_CNT  = OFF_SSQF + (size_t)B_SZ * 4;
  const size_t NEED_B   = OFF_CNT + 128;
  const size_t OFF_XBE  = NEED_B;
  const size_t NEED_A   = OFF_XBE + (size_t)NP * D_SZ * 2;
  if (ws_size < NEED_B) return;
  const int useA = (ws_size >= NEED_A) ? 1 : 0;

  char* ws = (char*)d_ws;
  unsigned short* exfn = (unsigned short*)(ws + OFF_EXFN);
  unsigned short* fnb  = (unsigned short*)(ws + OFF_FN);
  unsigned short* excT = (unsigned short*)(ws + OFF_EXCT);
  unsigned short* Wb   = (unsigned short*)(ws + OFF_WB);
  unsigned short* fnXb = (unsigned short*)(ws + OFF_FNXB);
  float* echo   = (float*)(ws + OFF_ECHO);
  float* ssqE   = (float*)(ws + OFF_SSQE);
  float* ssqF   = (float*)(ws + OFF_SSQF);
  float* counts = (float*)(ws + OFF_CNT);
  unsigned short* Xbe = (unsigned short*)(ws + OFF_XBE);

  // zero echo + ssqE + ssqF + counts (contiguous span)
  hipMemsetAsync(ws + OFF_ECHO, 0, OFF_CNT + 128 - OFF_ECHO, stream);

  if (useA) {
    hipMemsetAsync((char*)Xbe + (size_t)N_SZ * D_SZ * 2, 0,
                   (size_t)(NP - N_SZ) * D_SZ * 2, stream);
    conv8<<<dim3((N_SZ * D_SZ / 8 + 255) / 256), 256, 0, stream>>>(ex_feat, Xbe, N_SZ * D_SZ / 8);
  }
  conv8<<<dim3((B_SZ * D_SZ / 8 + 255) / 256), 256, 0, stream>>>(features, fnXb, B_SZ * D_SZ / 8);
  conv8<<<dim3((D_SZ * D_SZ / 8 + 255) / 256), 256, 0, stream>>>(W_g, Wb, D_SZ * D_SZ / 8);

  // grid: id = (y%8) + 8*(x + 6*(y/8)), y in [0,399), x in [0,6)
  proj_gemm2<<<dim3(8 * 6 * 50), 256, 0, stream>>>(fnXb, Xbe, ex_feat, Wb,
                                                   fnb, exfn, ssqF, ssqE, useA);

  excT_prep<<<dim3(NP / 64), 256, 0, stream>>>(ex_cls, excT, counts);  // clobbers Wb/fnXb (done)
  // grid: id = (x%8) + 8*(m + 8*(x/8)), x in [0,98), m in [0,8)
  echo_gemm<<<dim3(8 * 8 * 13), 256, 0, stream>>>(fnb, exfn, excT, ssqF, ssqE, echo);
  finalize<<<dim3(1), 1024, 0, stream>>>(echo, counts, labels, creps, out);
}